// Round 1
// baseline (490.123 us; speedup 1.0000x reference)
//
#include <hip/hip_runtime.h>
#include <math.h>

#define B_HALF 2048
#define N_TOT  4096
#define D_DIM  128
#define K_DIM  512
#define BM     128
#define BN     128
#define BK     32
#define NGRP   32   // 4096 / BN column groups

// ---------------------------------------------------------------------------
// a[i] = sum_d mu_i[d]^2 / var_i[d]
// ---------------------------------------------------------------------------
__global__ __launch_bounds__(128) void prep_a(const float* __restrict__ mu_x,
                                              const float* __restrict__ sigma_x,
                                              const float* __restrict__ mu_p,
                                              const float* __restrict__ sigma_p,
                                              float* __restrict__ a) {
  int i = blockIdx.x;        // 0..4095
  int d = threadIdx.x;       // 0..127
  const float* mup = (i < B_HALF) ? mu_x : mu_p;
  const float* sgp = (i < B_HALF) ? sigma_x : sigma_p;
  int gi = i & (B_HALF - 1);
  float mu = mup[gi * D_DIM + d];
  float s  = sgp[gi * D_DIM + d];
  float inv = 1.0f / (s * s);
  __shared__ float red[D_DIM];
  red[d] = mu * mu * inv;
  __syncthreads();
#pragma unroll
  for (int off = 64; off > 0; off >>= 1) {
    if (d < off) red[d] += red[d + off];
    __syncthreads();
  }
  if (d == 0) a[i] = red[0];
}

// feature generators: L_i = [inv, var+mu2, mu*inv, mu]
//                     R_j = [var+mu2, inv, -2mu, -2mu*inv]
__device__ __forceinline__ float lfeat(float mu, float sg, int f) {
  float var = sg * sg;
  if (f == 0) return 1.0f / var;
  if (f == 1) return var + mu * mu;
  if (f == 2) return mu / var;
  return mu;
}
__device__ __forceinline__ float rfeat(float mu, float sg, int f) {
  float var = sg * sg;
  if (f == 0) return var + mu * mu;
  if (f == 1) return 1.0f / var;
  if (f == 2) return -2.0f * mu;
  return -2.0f * mu / var;
}

// ---------------------------------------------------------------------------
// One block: 128 rows x 128 cols of the logit matrix, K = 512.
// Fused epilogue: S = c0 - c1*(G + a_i + a_j), diagonal -> -inf,
// positive column gets +to_add and is recorded; per-row online LSE partial.
// ---------------------------------------------------------------------------
__global__ __launch_bounds__(256) void tile_kernel(
    const float* __restrict__ mu_x, const float* __restrict__ sigma_x,
    const float* __restrict__ mu_p, const float* __restrict__ sigma_p,
    const float* __restrict__ a,
    float* __restrict__ lsep, float* __restrict__ pos, float to_add) {
  const float c0 = 640.0f;  // (D/2)/T
  const float c1 = 2.5f;    // 0.25/T
  int rb = blockIdx.x, cb = blockIdx.y;
  int tid = threadIdx.x;
  int tx = tid & 15, ty = tid >> 4;
  int rowBase = rb * BM, colBase = cb * BN;

  __shared__ float Lt[BM * BK];
  __shared__ float Rt[BN * BK];
  __shared__ float red[BM * 16 * 2];

  float acc[8][8];
#pragma unroll
  for (int r = 0; r < 8; ++r)
#pragma unroll
    for (int c = 0; c < 8; ++c) acc[r][c] = 0.0f;

  for (int kt = 0; kt < K_DIM; kt += BK) {
    int f  = kt >> 7;     // which of the 4 feature blocks
    int d0 = kt & 127;    // offset within D
#pragma unroll
    for (int t = 0; t < 4; ++t) {
      int e = tid + t * 256;         // float4 slot 0..1023
      int row = e >> 3, q = e & 7;   // 8 float4 per row (BK=32)
      int d = d0 + (q << 2);
      int sw4 = ((q ^ ((row >> 3) & 7)) << 2);  // XOR-swizzled quad
      {
        int g = rowBase + row;
        const float* mup = (g < B_HALF) ? mu_x : mu_p;
        const float* sgp = (g < B_HALF) ? sigma_x : sigma_p;
        int gi = g & (B_HALF - 1);
        float4 m4 = *(const float4*)(mup + gi * D_DIM + d);
        float4 s4 = *(const float4*)(sgp + gi * D_DIM + d);
        float4 v;
        v.x = lfeat(m4.x, s4.x, f); v.y = lfeat(m4.y, s4.y, f);
        v.z = lfeat(m4.z, s4.z, f); v.w = lfeat(m4.w, s4.w, f);
        *(float4*)(Lt + row * BK + sw4) = v;
      }
      {
        int g = colBase + row;
        const float* mup = (g < B_HALF) ? mu_x : mu_p;
        const float* sgp = (g < B_HALF) ? sigma_x : sigma_p;
        int gi = g & (B_HALF - 1);
        float4 m4 = *(const float4*)(mup + gi * D_DIM + d);
        float4 s4 = *(const float4*)(sgp + gi * D_DIM + d);
        float4 v;
        v.x = rfeat(m4.x, s4.x, f); v.y = rfeat(m4.y, s4.y, f);
        v.z = rfeat(m4.z, s4.z, f); v.w = rfeat(m4.w, s4.w, f);
        *(float4*)(Rt + row * BK + sw4) = v;
      }
    }
    __syncthreads();
#pragma unroll
    for (int q = 0; q < 8; ++q) {
      float4 la[8], rv[8];
#pragma unroll
      for (int r = 0; r < 8; ++r)
        la[r] = *(const float4*)(Lt + (ty * 8 + r) * BK + ((q ^ (ty & 7)) << 2));
#pragma unroll
      for (int c = 0; c < 8; ++c)
        rv[c] = *(const float4*)(Rt + (tx * 8 + c) * BK + ((q ^ (tx & 7)) << 2));
#pragma unroll
      for (int r = 0; r < 8; ++r)
#pragma unroll
        for (int c = 0; c < 8; ++c) {
          acc[r][c] = fmaf(la[r].x, rv[c].x, acc[r][c]);
          acc[r][c] = fmaf(la[r].y, rv[c].y, acc[r][c]);
          acc[r][c] = fmaf(la[r].z, rv[c].z, acc[r][c]);
          acc[r][c] = fmaf(la[r].w, rv[c].w, acc[r][c]);
        }
    }
    __syncthreads();
  }

  // ---- epilogue: logits, diag/positive handling, per-row partial LSE ----
  float aR[8], aC[8];
#pragma unroll
  for (int r = 0; r < 8; ++r) aR[r] = a[rowBase + ty * 8 + r];
#pragma unroll
  for (int c = 0; c < 8; ++c) aC[c] = a[colBase + tx * 8 + c];

#pragma unroll
  for (int r = 0; r < 8; ++r) {
    int grow = rowBase + ty * 8 + r;
    int prt = grow ^ B_HALF;  // positive partner column
    float m = -INFINITY;
    float sv[8];
#pragma unroll
    for (int c = 0; c < 8; ++c) {
      int gcol = colBase + tx * 8 + c;
      float S = c0 - c1 * (acc[r][c] + aR[r] + aC[c]);
      if (gcol == grow) {
        S = -INFINITY;                    // drop diagonal
      } else if (gcol == prt) {
        S += to_add;                      // weight branch on positive logit
        pos[grow] = S;                    // unique writer
      }
      sv[c] = S;
      m = fmaxf(m, S);
    }
    float ssum = 0.0f;
#pragma unroll
    for (int c = 0; c < 8; ++c) ssum += __expf(sv[c] - m);
    red[(ty * 8 + r) * 32 + tx * 2]     = m;
    red[(ty * 8 + r) * 32 + tx * 2 + 1] = ssum;
  }
  __syncthreads();
  if (tid < BM) {
    int row = tid;
    float m = -INFINITY;
#pragma unroll
    for (int g = 0; g < 16; ++g) m = fmaxf(m, red[row * 32 + g * 2]);
    float ssum = 0.0f;
#pragma unroll
    for (int g = 0; g < 16; ++g)
      ssum += red[row * 32 + g * 2 + 1] * __expf(red[row * 32 + g * 2] - m);
    lsep[(rowBase + row) * NGRP + cb] = m + logf(ssum);
  }
}

// ---------------------------------------------------------------------------
// Combine per-group LSE partials, subtract positive logit, mean, negate.
// hat_H = mean_i( LSE_i - S_pos_i )
// ---------------------------------------------------------------------------
__global__ __launch_bounds__(256) void final_reduce(
    const float* __restrict__ lsep, const float* __restrict__ pos,
    float* __restrict__ out) {
  int tid = threadIdx.x;
  int row = blockIdx.x * 256 + tid;
  float v[NGRP];
  float m = -INFINITY;
#pragma unroll
  for (int g = 0; g < NGRP; ++g) {
    v[g] = lsep[row * NGRP + g];
    m = fmaxf(m, v[g]);
  }
  float s = 0.0f;
#pragma unroll
  for (int g = 0; g < NGRP; ++g) s += __expf(v[g] - m);
  float contrib = (m + logf(s)) - pos[row];

  __shared__ float red[256];
  red[tid] = contrib;
  __syncthreads();
#pragma unroll
  for (int off = 128; off > 0; off >>= 1) {
    if (tid < off) red[tid] += red[tid + off];
    __syncthreads();
  }
  if (tid == 0) atomicAdd(out, red[0] * (1.0f / 4096.0f));
}

extern "C" void kernel_launch(void* const* d_in, const int* in_sizes, int n_in,
                              void* d_out, int out_size, void* d_ws, size_t ws_size,
                              hipStream_t stream) {
  const float* mu_x    = (const float*)d_in[1];
  const float* sigma_x = (const float*)d_in[2];
  const float* mu_p    = (const float*)d_in[3];
  const float* sigma_p = (const float*)d_in[4];
  float* out = (float*)d_out;

  char* ws = (char*)d_ws;
  float* a    = (float*)(ws);                     // 4096 * 4      = 16 KB
  float* lsep = (float*)(ws + 16384);             // 4096 * 32 * 4 = 512 KB
  float* pos  = (float*)(ws + 16384 + 524288);    // 4096 * 4      = 16 KB

  // to_add = -log((n_classes - 1/W) / (n_classes - 1)), n_classes = 4095, W = 5
  float to_add = (float)(-log((4095.0 - 1.0 / 5.0) / 4094.0));

  hipMemsetAsync(d_out, 0, sizeof(float), stream);
  prep_a<<<dim3(N_TOT), dim3(D_DIM), 0, stream>>>(mu_x, sigma_x, mu_p, sigma_p, a);
  tile_kernel<<<dim3(32, 32), dim3(256), 0, stream>>>(mu_x, sigma_x, mu_p, sigma_p,
                                                      a, lsep, pos, to_add);
  final_reduce<<<dim3(16), dim3(256), 0, stream>>>(lsep, pos, out);
}

// Round 2
// 56.223 us; speedup vs baseline: 8.7174x; 8.7174x over previous
//
#include <hip/hip_runtime.h>
#include <hip/hip_bf16.h>
#include <math.h>

typedef short bf16x8 __attribute__((ext_vector_type(8)));
typedef float f32x4 __attribute__((ext_vector_type(4)));

#define B_HALF 2048
#define N_TOT  4096
#define D_DIM  128
#define K_DIM  512
#define BM     128
#define BN     128
#define BK     64
#define NGRP   32

// ===========================================================================
// FAST PATH: bf16 feature precompute -> MFMA GEMM + fused LSE epilogue
// ===========================================================================

// L_i = [inv, var+mu2, mu*inv, mu]   (k-blocks of 128)
// R_j = [var+mu2, inv, -2mu, -2mu*inv]
// a_i = sum_d mu^2 * inv
__global__ __launch_bounds__(128) void prep_feat(
    const float* __restrict__ mu_x, const float* __restrict__ sigma_x,
    const float* __restrict__ mu_p, const float* __restrict__ sigma_p,
    __hip_bfloat16* __restrict__ Lf, __hip_bfloat16* __restrict__ Rf,
    float* __restrict__ a) {
  int i = blockIdx.x;
  int d = threadIdx.x;
  const float* mup = (i < B_HALF) ? mu_x : mu_p;
  const float* sgp = (i < B_HALF) ? sigma_x : sigma_p;
  int gi = i & (B_HALF - 1);
  float mu  = mup[gi * D_DIM + d];
  float sg  = sgp[gi * D_DIM + d];
  float var = sg * sg;
  float inv = 1.0f / var;
  float vm  = var + mu * mu;
  size_t base = (size_t)i * K_DIM;
  Lf[base + d]       = __float2bfloat16(inv);
  Lf[base + 128 + d] = __float2bfloat16(vm);
  Lf[base + 256 + d] = __float2bfloat16(mu * inv);
  Lf[base + 384 + d] = __float2bfloat16(mu);
  Rf[base + d]       = __float2bfloat16(vm);
  Rf[base + 128 + d] = __float2bfloat16(inv);
  Rf[base + 256 + d] = __float2bfloat16(-2.0f * mu);
  Rf[base + 384 + d] = __float2bfloat16(-2.0f * mu * inv);

  __shared__ float red[128];
  red[d] = mu * mu * inv;
  __syncthreads();
#pragma unroll
  for (int off = 64; off > 0; off >>= 1) {
    if (d < off) red[d] += red[d + off];
    __syncthreads();
  }
  if (d == 0) a[i] = red[0];
}

#define GLOAD16(src, dst)                                                     \
  __builtin_amdgcn_global_load_lds(                                           \
      (const __attribute__((address_space(1))) void*)(src),                   \
      (__attribute__((address_space(3))) void*)(dst), 16, 0, 0)

// 128x128 tile, 4 waves, each wave 64x64 = 4x4 fragments of 16x16x32 bf16.
// LDS linear-dest global_load_lds with pre-swizzled SOURCE (rule #21):
// logical byte c of row r lives at physical c ^ ((r&7)<<4).
__global__ __launch_bounds__(256) void gemm_lse(
    const __hip_bfloat16* __restrict__ Lf, const __hip_bfloat16* __restrict__ Rf,
    const float* __restrict__ a,
    float* __restrict__ lsep, float* __restrict__ pos, float to_add) {
  __shared__ char lt[BM * BK * 2];   // 16 KB
  __shared__ char rt[BN * BK * 2];   // 16 KB
  __shared__ float2 red[128][2];

  const int tid  = threadIdx.x;
  const int lane = tid & 63;
  const int wave = tid >> 6;
  const int rb = blockIdx.x, cb = blockIdx.y;
  const int rowBase = rb * BM, colBase = cb * BN;
  const int wr = wave >> 1, wc = wave & 1;

  f32x4 acc[4][4];
#pragma unroll
  for (int m = 0; m < 4; ++m)
#pragma unroll
    for (int n = 0; n < 4; ++n) acc[m][n] = (f32x4){0.f, 0.f, 0.f, 0.f};

  // staging geometry: one GLOAD16 covers 8 rows (1024B), lane l ->
  // row_in_chunk = l>>3, src col-byte = ((l&7)*16) ^ ((l>>3)<<4)
  const int ric   = lane >> 3;
  const int cbyte = ((lane & 7) * 16) ^ (ric << 4);
  const int swzk  = (lane & 7) << 4;       // read-side swizzle key
  const int rq    = lane >> 4;             // 16-lane group id

  for (int kk = 0; kk < K_DIM / BK; ++kk) {
    const char* lsrc = (const char*)Lf + (size_t)rowBase * (K_DIM * 2) + kk * (BK * 2);
    const char* rsrc = (const char*)Rf + (size_t)colBase * (K_DIM * 2) + kk * (BK * 2);
#pragma unroll
    for (int t = 0; t < 4; ++t) {
      int chunk = wave * 4 + t;
      GLOAD16(lsrc + (size_t)(chunk * 8 + ric) * (K_DIM * 2) + cbyte, lt + chunk * 1024);
      GLOAD16(rsrc + (size_t)(chunk * 8 + ric) * (K_DIM * 2) + cbyte, rt + chunk * 1024);
    }
    __syncthreads();   // drains vmcnt before reads
#pragma unroll
    for (int ks = 0; ks < 2; ++ks) {
      bf16x8 af[4], bg[4];
      const int kb = ks * 64 + rq * 16;    // logical byte offset in row
#pragma unroll
      for (int m = 0; m < 4; ++m) {
        int row = wr * 64 + m * 16 + (lane & 15);
        af[m] = *(const bf16x8*)(lt + row * 128 + (kb ^ swzk));
      }
#pragma unroll
      for (int n = 0; n < 4; ++n) {
        int row = wc * 64 + n * 16 + (lane & 15);
        bg[n] = *(const bf16x8*)(rt + row * 128 + (kb ^ swzk));
      }
#pragma unroll
      for (int m = 0; m < 4; ++m)
#pragma unroll
        for (int n = 0; n < 4; ++n)
          acc[m][n] = __builtin_amdgcn_mfma_f32_16x16x32_bf16(af[m], bg[n], acc[m][n], 0, 0, 0);
    }
    __syncthreads();
  }

  // ---- fused epilogue: logits + diag/pos + per-row LSE partial ----
  const float c0 = 640.0f;   // (D/2)/T
  const float c1 = 2.5f;     // 0.25/T
  float aR[4][4];
#pragma unroll
  for (int m = 0; m < 4; ++m)
#pragma unroll
    for (int v = 0; v < 4; ++v)
      aR[m][v] = a[rowBase + wr * 64 + m * 16 + rq * 4 + v];
  float aC[4];
#pragma unroll
  for (int n = 0; n < 4; ++n) aC[n] = a[colBase + wc * 64 + n * 16 + (lane & 15)];

#pragma unroll
  for (int m = 0; m < 4; ++m) {
#pragma unroll
    for (int v = 0; v < 4; ++v) {
      int grow = rowBase + wr * 64 + m * 16 + rq * 4 + v;
      int prt  = grow ^ B_HALF;
      float sv[4];
      float pmax = -INFINITY;
#pragma unroll
      for (int n = 0; n < 4; ++n) {
        int gcol = colBase + wc * 64 + n * 16 + (lane & 15);
        float S = c0 - c1 * (acc[m][n][v] + aR[m][v] + aC[n]);
        if (gcol == grow) {
          S = -INFINITY;                 // diagonal dropped
        } else if (gcol == prt) {
          S += to_add;                   // weight branch on positive logit
          pos[grow] = S;                 // unique writer
        }
        sv[n] = S;
        pmax = fmaxf(pmax, S);
      }
#pragma unroll
      for (int x = 1; x < 16; x <<= 1) pmax = fmaxf(pmax, __shfl_xor(pmax, x));
      float ps = 0.f;
#pragma unroll
      for (int n = 0; n < 4; ++n) ps += __expf(sv[n] - pmax);
#pragma unroll
      for (int x = 1; x < 16; x <<= 1) ps += __shfl_xor(ps, x);
      if ((lane & 15) == 0) {
        red[wr * 64 + m * 16 + rq * 4 + v][wc] = make_float2(pmax, ps);
      }
    }
  }
  __syncthreads();
  if (tid < 128) {
    float2 p0 = red[tid][0], p1 = red[tid][1];
    float M = fmaxf(p0.x, p1.x);
    float S = p0.y * __expf(p0.x - M) + p1.y * __expf(p1.x - M);
    lsep[(size_t)(rowBase + tid) * NGRP + cb] = M + logf(S);
  }
}

__global__ __launch_bounds__(256) void final_reduce(
    const float* __restrict__ lsep, const float* __restrict__ pos,
    float* __restrict__ out) {
  int tid = threadIdx.x;
  int row = blockIdx.x * 256 + tid;
  float v[NGRP];
  float m = -INFINITY;
#pragma unroll
  for (int g = 0; g < NGRP; ++g) {
    v[g] = lsep[row * NGRP + g];
    m = fmaxf(m, v[g]);
  }
  float s = 0.0f;
#pragma unroll
  for (int g = 0; g < NGRP; ++g) s += __expf(v[g] - m);
  float contrib = (m + logf(s)) - pos[row];

  __shared__ float red[256];
  red[tid] = contrib;
  __syncthreads();
#pragma unroll
  for (int off = 128; off > 0; off >>= 1) {
    if (tid < off) red[tid] += red[tid + off];
    __syncthreads();
  }
  if (tid == 0) atomicAdd(out, red[0] * (1.0f / 4096.0f));
}

// ===========================================================================
// FALLBACK (ws too small): round-1 fp32 path, known-correct
// ===========================================================================
__global__ __launch_bounds__(128) void prep_a(const float* __restrict__ mu_x,
                                              const float* __restrict__ sigma_x,
                                              const float* __restrict__ mu_p,
                                              const float* __restrict__ sigma_p,
                                              float* __restrict__ a) {
  int i = blockIdx.x;
  int d = threadIdx.x;
  const float* mup = (i < B_HALF) ? mu_x : mu_p;
  const float* sgp = (i < B_HALF) ? sigma_x : sigma_p;
  int gi = i & (B_HALF - 1);
  float mu = mup[gi * D_DIM + d];
  float s  = sgp[gi * D_DIM + d];
  float inv = 1.0f / (s * s);
  __shared__ float red[D_DIM];
  red[d] = mu * mu * inv;
  __syncthreads();
#pragma unroll
  for (int off = 64; off > 0; off >>= 1) {
    if (d < off) red[d] += red[d + off];
    __syncthreads();
  }
  if (d == 0) a[i] = red[0];
}

__device__ __forceinline__ float lfeat(float mu, float sg, int f) {
  float var = sg * sg;
  if (f == 0) return 1.0f / var;
  if (f == 1) return var + mu * mu;
  if (f == 2) return mu / var;
  return mu;
}
__device__ __forceinline__ float rfeat(float mu, float sg, int f) {
  float var = sg * sg;
  if (f == 0) return var + mu * mu;
  if (f == 1) return 1.0f / var;
  if (f == 2) return -2.0f * mu;
  return -2.0f * mu / var;
}

__global__ __launch_bounds__(256) void tile_kernel(
    const float* __restrict__ mu_x, const float* __restrict__ sigma_x,
    const float* __restrict__ mu_p, const float* __restrict__ sigma_p,
    const float* __restrict__ a,
    float* __restrict__ lsep, float* __restrict__ pos, float to_add) {
  const float c0 = 640.0f;
  const float c1 = 2.5f;
  int rb = blockIdx.x, cb = blockIdx.y;
  int tid = threadIdx.x;
  int tx = tid & 15, ty = tid >> 4;
  int rowBase = rb * BM, colBase = cb * BN;

  __shared__ float Lt[BM * 32];
  __shared__ float Rt[BN * 32];
  __shared__ float red[BM * 16 * 2];

  float acc[8][8];
#pragma unroll
  for (int r = 0; r < 8; ++r)
#pragma unroll
    for (int c = 0; c < 8; ++c) acc[r][c] = 0.0f;

  for (int kt = 0; kt < K_DIM; kt += 32) {
    int f  = kt >> 7;
    int d0 = kt & 127;
#pragma unroll
    for (int t = 0; t < 4; ++t) {
      int e = tid + t * 256;
      int row = e >> 3, q = e & 7;
      int d = d0 + (q << 2);
      int sw4 = ((q ^ ((row >> 3) & 7)) << 2);
      {
        int g = rowBase + row;
        const float* mup = (g < B_HALF) ? mu_x : mu_p;
        const float* sgp = (g < B_HALF) ? sigma_x : sigma_p;
        int gi = g & (B_HALF - 1);
        float4 m4 = *(const float4*)(mup + gi * D_DIM + d);
        float4 s4 = *(const float4*)(sgp + gi * D_DIM + d);
        float4 v;
        v.x = lfeat(m4.x, s4.x, f); v.y = lfeat(m4.y, s4.y, f);
        v.z = lfeat(m4.z, s4.z, f); v.w = lfeat(m4.w, s4.w, f);
        *(float4*)(Lt + row * 32 + sw4) = v;
      }
      {
        int g = colBase + row;
        const float* mup = (g < B_HALF) ? mu_x : mu_p;
        const float* sgp = (g < B_HALF) ? sigma_x : sigma_p;
        int gi = g & (B_HALF - 1);
        float4 m4 = *(const float4*)(mup + gi * D_DIM + d);
        float4 s4 = *(const float4*)(sgp + gi * D_DIM + d);
        float4 v;
        v.x = rfeat(m4.x, s4.x, f); v.y = rfeat(m4.y, s4.y, f);
        v.z = rfeat(m4.z, s4.z, f); v.w = rfeat(m4.w, s4.w, f);
        *(float4*)(Rt + row * 32 + sw4) = v;
      }
    }
    __syncthreads();
#pragma unroll
    for (int q = 0; q < 8; ++q) {
      float4 la[8], rv[8];
#pragma unroll
      for (int r = 0; r < 8; ++r)
        la[r] = *(const float4*)(Lt + (ty * 8 + r) * 32 + ((q ^ (ty & 7)) << 2));
#pragma unroll
      for (int c = 0; c < 8; ++c)
        rv[c] = *(const float4*)(Rt + (tx * 8 + c) * 32 + ((q ^ (tx & 7)) << 2));
#pragma unroll
      for (int r = 0; r < 8; ++r)
#pragma unroll
        for (int c = 0; c < 8; ++c) {
          acc[r][c] = fmaf(la[r].x, rv[c].x, acc[r][c]);
          acc[r][c] = fmaf(la[r].y, rv[c].y, acc[r][c]);
          acc[r][c] = fmaf(la[r].z, rv[c].z, acc[r][c]);
          acc[r][c] = fmaf(la[r].w, rv[c].w, acc[r][c]);
        }
    }
    __syncthreads();
  }

  float aR[8], aC[8];
#pragma unroll
  for (int r = 0; r < 8; ++r) aR[r] = a[rowBase + ty * 8 + r];
#pragma unroll
  for (int c = 0; c < 8; ++c) aC[c] = a[colBase + tx * 8 + c];

#pragma unroll
  for (int r = 0; r < 8; ++r) {
    int grow = rowBase + ty * 8 + r;
    int prt = grow ^ B_HALF;
    float m = -INFINITY;
    float sv[8];
#pragma unroll
    for (int c = 0; c < 8; ++c) {
      int gcol = colBase + tx * 8 + c;
      float S = c0 - c1 * (acc[r][c] + aR[r] + aC[c]);
      if (gcol == grow) {
        S = -INFINITY;
      } else if (gcol == prt) {
        S += to_add;
        pos[grow] = S;
      }
      sv[c] = S;
      m = fmaxf(m, S);
    }
    float ssum = 0.0f;
#pragma unroll
    for (int c = 0; c < 8; ++c) ssum += __expf(sv[c] - m);
    red[(ty * 8 + r) * 32 + tx * 2]     = m;
    red[(ty * 8 + r) * 32 + tx * 2 + 1] = ssum;
  }
  __syncthreads();
  if (tid < BM) {
    int row = tid;
    float m = -INFINITY;
#pragma unroll
    for (int g = 0; g < 16; ++g) m = fmaxf(m, red[row * 32 + g * 2]);
    float ssum = 0.0f;
#pragma unroll
    for (int g = 0; g < 16; ++g)
      ssum += red[row * 32 + g * 2 + 1] * __expf(red[row * 32 + g * 2] - m);
    lsep[(rowBase + row) * NGRP + cb] = m + logf(ssum);
  }
}

// ===========================================================================
extern "C" void kernel_launch(void* const* d_in, const int* in_sizes, int n_in,
                              void* d_out, int out_size, void* d_ws, size_t ws_size,
                              hipStream_t stream) {
  const float* mu_x    = (const float*)d_in[1];
  const float* sigma_x = (const float*)d_in[2];
  const float* mu_p    = (const float*)d_in[3];
  const float* sigma_p = (const float*)d_in[4];
  float* out = (float*)d_out;

  float to_add = (float)(-log((4095.0 - 1.0 / 5.0) / 4094.0));
  hipMemsetAsync(d_out, 0, sizeof(float), stream);

  const size_t featB = (size_t)N_TOT * K_DIM * 2;          // 4 MB each
  const size_t need  = 2 * featB + 16384 + 524288 + 16384; // ~8.9 MB

  char* ws = (char*)d_ws;
  if (ws_size >= need) {
    __hip_bfloat16* Lf = (__hip_bfloat16*)(ws);
    __hip_bfloat16* Rf = (__hip_bfloat16*)(ws + featB);
    float* a    = (float*)(ws + 2 * featB);
    float* lsep = (float*)(ws + 2 * featB + 16384);
    float* pos  = (float*)(ws + 2 * featB + 16384 + 524288);

    prep_feat<<<dim3(N_TOT), dim3(D_DIM), 0, stream>>>(mu_x, sigma_x, mu_p, sigma_p, Lf, Rf, a);
    gemm_lse<<<dim3(32, 32), dim3(256), 0, stream>>>(Lf, Rf, a, lsep, pos, to_add);
    final_reduce<<<dim3(16), dim3(256), 0, stream>>>(lsep, pos, out);
  } else {
    float* a    = (float*)(ws);
    float* lsep = (float*)(ws + 16384);
    float* pos  = (float*)(ws + 16384 + 524288);
    prep_a<<<dim3(N_TOT), dim3(D_DIM), 0, stream>>>(mu_x, sigma_x, mu_p, sigma_p, a);
    tile_kernel<<<dim3(32, 32), dim3(256), 0, stream>>>(mu_x, sigma_x, mu_p, sigma_p,
                                                        a, lsep, pos, to_add);
    final_reduce<<<dim3(16), dim3(256), 0, stream>>>(lsep, pos, out);
  }
}

// Round 3
// 53.810 us; speedup vs baseline: 9.1084x; 1.0448x over previous
//
#include <hip/hip_runtime.h>
#include <hip/hip_bf16.h>
#include <math.h>

typedef short bf16x8 __attribute__((ext_vector_type(8)));
typedef float f32x4 __attribute__((ext_vector_type(4)));

#define B_HALF 2048
#define N_TOT  4096
#define D_DIM  128
#define K_DIM  512
#define BM     128
#define BN     128
#define BK     64
#define NGRP   32

// ===========================================================================
// FAST PATH: bf16 features -> triangular MFMA GEMM + fused two-sided LSE
// ===========================================================================

// L_i = [inv, var+mu2, mu*inv, mu]  (k-blocks of 128)
// R_j = [var+mu2, inv, -2mu, -2mu*inv]
// a_i = sum_d mu^2 * inv      (L_i . R_j is symmetric in i<->j)
__global__ __launch_bounds__(128) void prep_feat(
    const float* __restrict__ mu_x, const float* __restrict__ sigma_x,
    const float* __restrict__ mu_p, const float* __restrict__ sigma_p,
    __hip_bfloat16* __restrict__ Lf, __hip_bfloat16* __restrict__ Rf,
    float* __restrict__ a) {
  int i = blockIdx.x;
  int d = threadIdx.x;
  const float* mup = (i < B_HALF) ? mu_x : mu_p;
  const float* sgp = (i < B_HALF) ? sigma_x : sigma_p;
  int gi = i & (B_HALF - 1);
  float mu  = mup[gi * D_DIM + d];
  float sg  = sgp[gi * D_DIM + d];
  float var = sg * sg;
  float inv = 1.0f / var;
  float vm  = var + mu * mu;
  size_t base = (size_t)i * K_DIM;
  Lf[base + d]       = __float2bfloat16(inv);
  Lf[base + 128 + d] = __float2bfloat16(vm);
  Lf[base + 256 + d] = __float2bfloat16(mu * inv);
  Lf[base + 384 + d] = __float2bfloat16(mu);
  Rf[base + d]       = __float2bfloat16(vm);
  Rf[base + 128 + d] = __float2bfloat16(inv);
  Rf[base + 256 + d] = __float2bfloat16(-2.0f * mu);
  Rf[base + 384 + d] = __float2bfloat16(-2.0f * mu * inv);

  float v = mu * mu * inv;
#pragma unroll
  for (int x = 1; x < 64; x <<= 1) v += __shfl_xor(v, x);
  __shared__ float wsum[2];
  if ((d & 63) == 0) wsum[d >> 6] = v;
  __syncthreads();
  if (d == 0) a[i] = wsum[0] + wsum[1];
}

#define GLOAD16(src, dst)                                                     \
  __builtin_amdgcn_global_load_lds(                                           \
      (const __attribute__((address_space(1))) void*)(src),                   \
      (__attribute__((address_space(3))) void*)(dst), 16, 0, 0)

// Triangular tile (rb<=cb): 128x128, 4 waves x (4x4 of 16x16x32 bf16).
// LDS: linear dest + pre-swizzled global source, read-side XOR (rule #21).
__global__ __launch_bounds__(256) void gemm_lse(
    const __hip_bfloat16* __restrict__ Lf, const __hip_bfloat16* __restrict__ Rf,
    const float* __restrict__ a,
    float* __restrict__ lsep, float* __restrict__ pos, float to_add) {
  __shared__ char lt[BM * BK * 2];   // 16 KB
  __shared__ char rt[BN * BK * 2];   // 16 KB
  __shared__ float2 red[128][2];

  // decode triangular block index: t -> (rb, cb), rb<=cb
  int t = blockIdx.x;
  int rb = 0;
  while (t >= 32 - rb) { t -= 32 - rb; ++rb; }
  const int cb = rb + t;

  const int tid  = threadIdx.x;
  const int lane = tid & 63;
  const int wave = tid >> 6;
  const int rowBase = rb * BM, colBase = cb * BN;
  const int wr = wave >> 1, wc = wave & 1;
  const int lx = lane & 15;
  const int rq = lane >> 4;

  f32x4 acc[4][4];
#pragma unroll
  for (int m = 0; m < 4; ++m)
#pragma unroll
    for (int n = 0; n < 4; ++n) acc[m][n] = (f32x4){0.f, 0.f, 0.f, 0.f};

  const int ric   = lane >> 3;
  const int cbyte = ((lane & 7) * 16) ^ (ric << 4);
  const int swzk  = (lane & 7) << 4;

  for (int kk = 0; kk < K_DIM / BK; ++kk) {
    const char* lsrc = (const char*)Lf + (size_t)rowBase * (K_DIM * 2) + kk * (BK * 2);
    const char* rsrc = (const char*)Rf + (size_t)colBase * (K_DIM * 2) + kk * (BK * 2);
#pragma unroll
    for (int t4 = 0; t4 < 4; ++t4) {
      int chunk = wave * 4 + t4;
      GLOAD16(lsrc + (size_t)(chunk * 8 + ric) * (K_DIM * 2) + cbyte, lt + chunk * 1024);
      GLOAD16(rsrc + (size_t)(chunk * 8 + ric) * (K_DIM * 2) + cbyte, rt + chunk * 1024);
    }
    __syncthreads();
#pragma unroll
    for (int ks = 0; ks < 2; ++ks) {
      bf16x8 af[4], bg[4];
      const int kb = ks * 64 + rq * 16;
#pragma unroll
      for (int m = 0; m < 4; ++m) {
        int row = wr * 64 + m * 16 + lx;
        af[m] = *(const bf16x8*)(lt + row * 128 + (kb ^ swzk));
      }
#pragma unroll
      for (int n = 0; n < 4; ++n) {
        int row = wc * 64 + n * 16 + lx;
        bg[n] = *(const bf16x8*)(rt + row * 128 + (kb ^ swzk));
      }
#pragma unroll
      for (int m = 0; m < 4; ++m)
#pragma unroll
        for (int n = 0; n < 4; ++n)
          acc[m][n] = __builtin_amdgcn_mfma_f32_16x16x32_bf16(af[m], bg[n], acc[m][n], 0, 0, 0);
    }
    __syncthreads();
  }

  // ---- epilogue ----
  const float c0 = 640.0f;   // (D/2)/T
  const float c1 = 2.5f;     // 0.25/T
  float aR[4][4];
#pragma unroll
  for (int m = 0; m < 4; ++m)
#pragma unroll
    for (int v = 0; v < 4; ++v)
      aR[m][v] = a[rowBase + wr * 64 + m * 16 + rq * 4 + v];
  float aC[4];
#pragma unroll
  for (int n = 0; n < 4; ++n) aC[n] = a[colBase + wc * 64 + n * 16 + lx];

  // pass 1: acc -> S (diag -> -inf, positive gets to_add; pos[] unique writes)
#pragma unroll
  for (int m = 0; m < 4; ++m)
#pragma unroll
    for (int n = 0; n < 4; ++n)
#pragma unroll
      for (int v = 0; v < 4; ++v) {
        int grow = rowBase + wr * 64 + m * 16 + rq * 4 + v;
        int gcol = colBase + wc * 64 + n * 16 + lx;
        float S = c0 - c1 * (acc[m][n][v] + aR[m][v] + aC[n]);
        if (gcol == grow) {
          S = -INFINITY;
        } else if (gcol == (grow ^ B_HALF)) {
          S += to_add;
          pos[grow] = S;   // S symmetric: same value is row gcol's positive
          pos[gcol] = S;
        }
        acc[m][n][v] = S;
      }

  // pass 2: row-wise partials -> lsep[row][cb]
#pragma unroll
  for (int m = 0; m < 4; ++m)
#pragma unroll
    for (int v = 0; v < 4; ++v) {
      float pm = -INFINITY;
#pragma unroll
      for (int n = 0; n < 4; ++n) pm = fmaxf(pm, acc[m][n][v]);
#pragma unroll
      for (int x = 1; x < 16; x <<= 1) pm = fmaxf(pm, __shfl_xor(pm, x));
      float ps = 0.f;
#pragma unroll
      for (int n = 0; n < 4; ++n) ps += __expf(acc[m][n][v] - pm);
#pragma unroll
      for (int x = 1; x < 16; x <<= 1) ps += __shfl_xor(ps, x);
      if (lx == 0) red[wr * 64 + m * 16 + rq * 4 + v][wc] = make_float2(pm, ps);
    }
  __syncthreads();
  if (tid < 128) {
    float2 p0 = red[tid][0], p1 = red[tid][1];
    float M = fmaxf(p0.x, p1.x);
    float S = p0.y * __expf(p0.x - M) + p1.y * __expf(p1.x - M);
    lsep[(size_t)(rowBase + tid) * NGRP + cb] = M + logf(S);
  }

  // pass 3: column-wise partials -> lsep[col][rb]   (skip on diagonal tiles)
  if (rb != cb) {
    __syncthreads();   // red reuse
#pragma unroll
    for (int n = 0; n < 4; ++n) {
      float cm = -INFINITY;
#pragma unroll
      for (int m = 0; m < 4; ++m)
#pragma unroll
        for (int v = 0; v < 4; ++v) cm = fmaxf(cm, acc[m][n][v]);
      cm = fmaxf(cm, __shfl_xor(cm, 16));
      cm = fmaxf(cm, __shfl_xor(cm, 32));
      float cs = 0.f;
#pragma unroll
      for (int m = 0; m < 4; ++m)
#pragma unroll
        for (int v = 0; v < 4; ++v) cs += __expf(acc[m][n][v] - cm);
      cs += __shfl_xor(cs, 16);
      cs += __shfl_xor(cs, 32);
      if (lane < 16) red[wc * 64 + n * 16 + lane][wr] = make_float2(cm, cs);
    }
    __syncthreads();
    if (tid < 128) {
      float2 p0 = red[tid][0], p1 = red[tid][1];
      float M = fmaxf(p0.x, p1.x);
      float S = p0.y * __expf(p0.x - M) + p1.y * __expf(p1.x - M);
      lsep[(size_t)(colBase + tid) * NGRP + rb] = M + logf(S);
    }
  }
}

// stage 1: 16 blocks x 256 rows -> partial sums (deterministic in-block tree)
__global__ __launch_bounds__(256) void final_reduce(
    const float* __restrict__ lsep, const float* __restrict__ pos,
    float* __restrict__ partial) {
  int tid = threadIdx.x;
  int row = blockIdx.x * 256 + tid;
  float v[NGRP];
  float m = -INFINITY;
#pragma unroll
  for (int g = 0; g < NGRP; ++g) {
    v[g] = lsep[row * NGRP + g];
    m = fmaxf(m, v[g]);
  }
  float s = 0.0f;
#pragma unroll
  for (int g = 0; g < NGRP; ++g) s += __expf(v[g] - m);
  float contrib = (m + logf(s)) - pos[row];

  __shared__ float red[256];
  red[tid] = contrib;
  __syncthreads();
#pragma unroll
  for (int off = 128; off > 0; off >>= 1) {
    if (tid < off) red[tid] += red[tid + off];
    __syncthreads();
  }
  if (tid == 0) partial[blockIdx.x] = red[0];
}

// stage 2: 1 wave sums 16 partials -> out (fixed order, no atomics)
__global__ __launch_bounds__(64) void final_sum(
    const float* __restrict__ partial, float* __restrict__ out) {
  int tid = threadIdx.x;
  float v = (tid < 16) ? partial[tid] : 0.f;
#pragma unroll
  for (int x = 1; x < 16; x <<= 1) v += __shfl_xor(v, x);
  if (tid == 0) *out = v * (1.0f / 4096.0f);
}

// ===========================================================================
// FALLBACK (ws too small): round-1 fp32 path, known-correct
// ===========================================================================
__global__ __launch_bounds__(128) void prep_a(const float* __restrict__ mu_x,
                                              const float* __restrict__ sigma_x,
                                              const float* __restrict__ mu_p,
                                              const float* __restrict__ sigma_p,
                                              float* __restrict__ a) {
  int i = blockIdx.x;
  int d = threadIdx.x;
  const float* mup = (i < B_HALF) ? mu_x : mu_p;
  const float* sgp = (i < B_HALF) ? sigma_x : sigma_p;
  int gi = i & (B_HALF - 1);
  float mu = mup[gi * D_DIM + d];
  float s  = sgp[gi * D_DIM + d];
  float inv = 1.0f / (s * s);
  __shared__ float red[D_DIM];
  red[d] = mu * mu * inv;
  __syncthreads();
#pragma unroll
  for (int off = 64; off > 0; off >>= 1) {
    if (d < off) red[d] += red[d + off];
    __syncthreads();
  }
  if (d == 0) a[i] = red[0];
}

__device__ __forceinline__ float lfeat(float mu, float sg, int f) {
  float var = sg * sg;
  if (f == 0) return 1.0f / var;
  if (f == 1) return var + mu * mu;
  if (f == 2) return mu / var;
  return mu;
}
__device__ __forceinline__ float rfeat(float mu, float sg, int f) {
  float var = sg * sg;
  if (f == 0) return var + mu * mu;
  if (f == 1) return 1.0f / var;
  if (f == 2) return -2.0f * mu;
  return -2.0f * mu / var;
}

__global__ __launch_bounds__(256) void tile_kernel(
    const float* __restrict__ mu_x, const float* __restrict__ sigma_x,
    const float* __restrict__ mu_p, const float* __restrict__ sigma_p,
    const float* __restrict__ a,
    float* __restrict__ lsep, float* __restrict__ pos, float to_add) {
  const float c0 = 640.0f;
  const float c1 = 2.5f;
  int rb = blockIdx.x, cb = blockIdx.y;
  int tid = threadIdx.x;
  int tx = tid & 15, ty = tid >> 4;
  int rowBase = rb * BM, colBase = cb * BN;

  __shared__ float Lt[BM * 32];
  __shared__ float Rt[BN * 32];
  __shared__ float red[BM * 16 * 2];

  float acc[8][8];
#pragma unroll
  for (int r = 0; r < 8; ++r)
#pragma unroll
    for (int c = 0; c < 8; ++c) acc[r][c] = 0.0f;

  for (int kt = 0; kt < K_DIM; kt += 32) {
    int f  = kt >> 7;
    int d0 = kt & 127;
#pragma unroll
    for (int t = 0; t < 4; ++t) {
      int e = tid + t * 256;
      int row = e >> 3, q = e & 7;
      int d = d0 + (q << 2);
      int sw4 = ((q ^ ((row >> 3) & 7)) << 2);
      {
        int g = rowBase + row;
        const float* mup = (g < B_HALF) ? mu_x : mu_p;
        const float* sgp = (g < B_HALF) ? sigma_x : sigma_p;
        int gi = g & (B_HALF - 1);
        float4 m4 = *(const float4*)(mup + gi * D_DIM + d);
        float4 s4 = *(const float4*)(sgp + gi * D_DIM + d);
        float4 v;
        v.x = lfeat(m4.x, s4.x, f); v.y = lfeat(m4.y, s4.y, f);
        v.z = lfeat(m4.z, s4.z, f); v.w = lfeat(m4.w, s4.w, f);
        *(float4*)(Lt + row * 32 + sw4) = v;
      }
      {
        int g = colBase + row;
        const float* mup = (g < B_HALF) ? mu_x : mu_p;
        const float* sgp = (g < B_HALF) ? sigma_x : sigma_p;
        int gi = g & (B_HALF - 1);
        float4 m4 = *(const float4*)(mup + gi * D_DIM + d);
        float4 s4 = *(const float4*)(sgp + gi * D_DIM + d);
        float4 v;
        v.x = rfeat(m4.x, s4.x, f); v.y = rfeat(m4.y, s4.y, f);
        v.z = rfeat(m4.z, s4.z, f); v.w = rfeat(m4.w, s4.w, f);
        *(float4*)(Rt + row * 32 + sw4) = v;
      }
    }
    __syncthreads();
#pragma unroll
    for (int q = 0; q < 8; ++q) {
      float4 la[8], rv[8];
#pragma unroll
      for (int r = 0; r < 8; ++r)
        la[r] = *(const float4*)(Lt + (ty * 8 + r) * 32 + ((q ^ (ty & 7)) << 2));
#pragma unroll
      for (int c = 0; c < 8; ++c)
        rv[c] = *(const float4*)(Rt + (tx * 8 + c) * 32 + ((q ^ (tx & 7)) << 2));
#pragma unroll
      for (int r = 0; r < 8; ++r)
#pragma unroll
        for (int c = 0; c < 8; ++c) {
          acc[r][c] = fmaf(la[r].x, rv[c].x, acc[r][c]);
          acc[r][c] = fmaf(la[r].y, rv[c].y, acc[r][c]);
          acc[r][c] = fmaf(la[r].z, rv[c].z, acc[r][c]);
          acc[r][c] = fmaf(la[r].w, rv[c].w, acc[r][c]);
        }
    }
    __syncthreads();
  }

  float aR[8], aC[8];
#pragma unroll
  for (int r = 0; r < 8; ++r) aR[r] = a[rowBase + ty * 8 + r];
#pragma unroll
  for (int c = 0; c < 8; ++c) aC[c] = a[colBase + tx * 8 + c];

#pragma unroll
  for (int r = 0; r < 8; ++r) {
    int grow = rowBase + ty * 8 + r;
    int prt = grow ^ B_HALF;
    float m = -INFINITY;
    float sv[8];
#pragma unroll
    for (int c = 0; c < 8; ++c) {
      int gcol = colBase + tx * 8 + c;
      float S = c0 - c1 * (acc[r][c] + aR[r] + aC[c]);
      if (gcol == grow) {
        S = -INFINITY;
      } else if (gcol == prt) {
        S += to_add;
        pos[grow] = S;
      }
      sv[c] = S;
      m = fmaxf(m, S);
    }
    float ssum = 0.0f;
#pragma unroll
    for (int c = 0; c < 8; ++c) ssum += __expf(sv[c] - m);
    red[(ty * 8 + r) * 32 + tx * 2]     = m;
    red[(ty * 8 + r) * 32 + tx * 2 + 1] = ssum;
  }
  __syncthreads();
  if (tid < BM) {
    int row = tid;
    float m = -INFINITY;
#pragma unroll
    for (int g = 0; g < 16; ++g) m = fmaxf(m, red[row * 32 + g * 2]);
    float ssum = 0.0f;
#pragma unroll
    for (int g = 0; g < 16; ++g)
      ssum += red[row * 32 + g * 2 + 1] * __expf(red[row * 32 + g * 2] - m);
    lsep[(rowBase + row) * NGRP + cb] = m + logf(ssum);
  }
}

// ===========================================================================
extern "C" void kernel_launch(void* const* d_in, const int* in_sizes, int n_in,
                              void* d_out, int out_size, void* d_ws, size_t ws_size,
                              hipStream_t stream) {
  const float* mu_x    = (const float*)d_in[1];
  const float* sigma_x = (const float*)d_in[2];
  const float* mu_p    = (const float*)d_in[3];
  const float* sigma_p = (const float*)d_in[4];
  float* out = (float*)d_out;

  float to_add = (float)(-log((4095.0 - 1.0 / 5.0) / 4094.0));

  const size_t featB = (size_t)N_TOT * K_DIM * 2;                 // 4 MB each
  const size_t need  = 2 * featB + 16384 + 524288 + 16384 + 256;  // ~8.9 MB

  char* ws = (char*)d_ws;
  if (ws_size >= need) {
    __hip_bfloat16* Lf = (__hip_bfloat16*)(ws);
    __hip_bfloat16* Rf = (__hip_bfloat16*)(ws + featB);
    float* a       = (float*)(ws + 2 * featB);
    float* lsep    = (float*)(ws + 2 * featB + 16384);
    float* pos     = (float*)(ws + 2 * featB + 16384 + 524288);
    float* partial = (float*)(ws + 2 * featB + 16384 + 524288 + 16384);

    prep_feat<<<dim3(N_TOT), dim3(D_DIM), 0, stream>>>(mu_x, sigma_x, mu_p, sigma_p, Lf, Rf, a);
    gemm_lse<<<dim3(528), dim3(256), 0, stream>>>(Lf, Rf, a, lsep, pos, to_add);
    final_reduce<<<dim3(16), dim3(256), 0, stream>>>(lsep, pos, partial);
    final_sum<<<dim3(1), dim3(64), 0, stream>>>(partial, out);
  } else {
    float* a    = (float*)(ws);
    float* lsep = (float*)(ws + 16384);
    float* pos  = (float*)(ws + 16384 + 524288);
    float* partial = (float*)(ws + 16384 + 524288 + 16384);
    prep_a<<<dim3(N_TOT), dim3(D_DIM), 0, stream>>>(mu_x, sigma_x, mu_p, sigma_p, a);
    tile_kernel<<<dim3(32, 32), dim3(256), 0, stream>>>(mu_x, sigma_x, mu_p, sigma_p,
                                                        a, lsep, pos, to_add);
    final_reduce<<<dim3(16), dim3(256), 0, stream>>>(lsep, pos, partial);
    final_sum<<<dim3(1), dim3(64), 0, stream>>>(partial, out);
  }
}